// Round 16
// baseline (49.523 us; speedup 1.0000x reference)
//
#include <hip/hip_runtime.h>
#include <math.h>

// YOLOv3 detection-head decode — persistent 2-group pipelined blocks.
// prediction: [B=32, 255, 52, 52] f32 ; anchors: [3,2] f32
// out: [B, 52*52*3, 85] f32 ; flat out elem = (b*2704 + s)*255 + c.
//
// Unit (group) = 16 consecutive s: input = one aligned 64B line per c-row
// (255 exclusive lines); output = 4080 contiguous floats = 255 aligned
// lines. Decode folded into the LOAD phase (c per-thread constant; special
// columns hit 3/16 wave-iters); store phase is a pure LDS->global copy.
//
// R16 change vs R15: grid 2704 = 8 xcd x 338 slots; each block owns TWO
// groups of the same XCD range (g0, g0+338) and pipelines them: g1's
// global loads issue before g0's store phase, so g1's HBM read latency
// hides under g0's write stream + barrier. Halves dispatch count; keeps
// 16,320B LDS -> 8 blocks/CU.

#define GG 52
#define NROWS 255
#define PLANE 2704             // 52*52, flat s
#define L2E 1.442695040889f

typedef float f32x4 __attribute__((ext_vector_type(4)));

__device__ __forceinline__ float fast_sigmoid(float x) {
    return __builtin_amdgcn_rcpf(1.0f + __builtin_amdgcn_exp2f(-L2E * x));
}

__global__ __launch_bounds__(256, 8)
void detect_decode_kernel(const float* __restrict__ in,
                          const float* __restrict__ anchors,
                          float* __restrict__ out) {
    __shared__ float tile[16 * NROWS];   // 16,320 B, FINAL values, output order

    const int B    = blockIdx.x;         // 2704 = 8 * 338
    const int xcd  = B & 7;
    const int slot = B >> 3;             // 0..337
    const int g0   = xcd * 676 + slot;   // groups g0 and g0+338, same XCD
    const int t    = threadIdx.x;

    // per-thread element indices (16 s-values * 255 c = 1020 float4)
    const int i0 = t;
    const int i1 = t + 256;
    const int i2 = t + 512;
    const int i3 = (t + 768 < 1020) ? t + 768 : 1019;   // clamp (c=254: plain)

    const float a0x = anchors[0], a0y = anchors[1];
    const float a1x = anchors[2], a1y = anchors[3];
    const float a2x = anchors[4], a2y = anchors[5];

    // ---- group geometry helpers (block-uniform scalar math) ----
    auto geom = [&](int g, const float*& src, float*& dst, int& gj0, int& rem0) {
        const int b  = g / 169;
        const int s0 = (g - b * 169) * 16;
        src  = in  + (size_t)b * NROWS * PLANE + s0;
        dst  = out + ((size_t)b * PLANE + s0) * NROWS;
        gj0  = s0 / GG;
        rem0 = s0 - gj0 * GG;
    };

    auto load4 = [&](const float* __restrict__ src, f32x4* v) {
        v[0] = *reinterpret_cast<const f32x4*>(src + (size_t)(i0 >> 2) * PLANE + (i0 & 3) * 4);
        v[1] = *reinterpret_cast<const f32x4*>(src + (size_t)(i1 >> 2) * PLANE + (i1 & 3) * 4);
        v[2] = *reinterpret_cast<const f32x4*>(src + (size_t)(i2 >> 2) * PLANE + (i2 & 3) * 4);
        v[3] = *reinterpret_cast<const f32x4*>(src + (size_t)(i3 >> 2) * PLANE + (i3 & 3) * 4);
    };

    auto decode_scatter = [&](const f32x4* v, int gj0, int rem0) {
        #pragma unroll
        for (int it = 0; it < 4; ++it) {
            const int idx = (it == 0) ? i0 : (it == 1) ? i1 : (it == 2) ? i2 : i3;
            const int c = idx >> 2;
            const int q = idx & 3;
            const f32x4 u = v[it];

            f32x4 r;
            r.x = fast_sigmoid(u.x);
            r.y = fast_sigmoid(u.y);
            r.z = fast_sigmoid(u.z);
            r.w = fast_sigmoid(u.w);

            const bool sp0 = c < 4;
            const bool sp1 = (unsigned)(c - 85)  < 4u;
            const bool sp2 = (unsigned)(c - 170) < 4u;
            if (__builtin_expect(sp0 | sp1 | sp2, 0)) {
                const int attr = sp0 ? c : (sp1 ? c - 85 : c - 170);
                const float ancx = sp0 ? a0x : (sp1 ? a1x : a2x);
                const float ancy = sp0 ? a0y : (sp1 ? a1y : a2y);
                const float anc  = (attr == 2) ? ancx : ancy;
                #pragma unroll
                for (int k = 0; k < 4; ++k) {
                    const int rem = rem0 + 4 * q + k;   // < 68: one wrap max
                    const int wv  = (rem >= GG) ? 1 : 0;
                    const int gi  = rem - (wv ? GG : 0);
                    const int gj  = gj0 + wv;
                    const float x  = u[k];
                    const float sg = r[k];
                    float rr;
                    if (attr == 0)      rr = (sg + (float)gi) * 8.0f;
                    else if (attr == 1) rr = (sg + (float)gj) * 8.0f;
                    else                rr = __builtin_amdgcn_exp2f(L2E * x) * anc;
                    r[k] = rr;
                }
            }

            const int e = q * 4 * NROWS + c;   // (c, s_l=4q+k) -> s_l*255+c
            tile[e            ] = r.x;
            tile[e +     NROWS] = r.y;
            tile[e + 2 * NROWS] = r.z;
            tile[e + 3 * NROWS] = r.w;
        }
    };

    auto read_store = [&](float* __restrict__ dst) {
        const f32x4 u0 = *reinterpret_cast<const f32x4*>(&tile[4 * i0]);
        const f32x4 u1 = *reinterpret_cast<const f32x4*>(&tile[4 * i1]);
        const f32x4 u2 = *reinterpret_cast<const f32x4*>(&tile[4 * i2]);
        const f32x4 u3 = *reinterpret_cast<const f32x4*>(&tile[4 * i3]);
        *reinterpret_cast<f32x4*>(dst + 4 * i0) = u0;
        *reinterpret_cast<f32x4*>(dst + 4 * i1) = u1;
        *reinterpret_cast<f32x4*>(dst + 4 * i2) = u2;
        *reinterpret_cast<f32x4*>(dst + 4 * i3) = u3;
    };

    // ================= pipeline =================
    const float* src0; float* dst0; int gj00, rem00;
    const float* src1; float* dst1; int gj01, rem01;
    geom(g0,       src0, dst0, gj00, rem00);
    geom(g0 + 338, src1, dst1, gj01, rem01);

    f32x4 v[4];

    // group 0: load + decode + scatter
    load4(src0, v);
    decode_scatter(v, gj00, rem00);
    __syncthreads();

    // issue group 1 loads EARLY (latency hides under g0's store phase)
    f32x4 w[4];
    load4(src1, w);

    // group 0: read tile + store
    read_store(dst0);
    __syncthreads();                 // all waves done reading tile

    // group 1: decode (vmcnt waits here) + scatter
    decode_scatter(w, gj01, rem01);
    __syncthreads();

    // group 1: read tile + store
    read_store(dst1);
}

extern "C" void kernel_launch(void* const* d_in, const int* in_sizes, int n_in,
                              void* d_out, int out_size, void* d_ws, size_t ws_size,
                              hipStream_t stream) {
    const float* pred    = (const float*)d_in[0];
    const float* anchors = (const float*)d_in[1];
    float* out = (float*)d_out;

    detect_decode_kernel<<<2704, 256, 0, stream>>>(pred, anchors, out);
}

// Round 17
// 31.797 us; speedup vs baseline: 1.5575x; 1.5575x over previous
//
#include <hip/hip_runtime.h>
#include <math.h>

// YOLOv3 detection-head decode — persistent 2-group pipelined blocks,
// spill-proof (named regs only; R16's lambda-pointer arrays went to scratch:
// VGPR=24, WRITE 167 MB. All staging now in named scalars, helpers by-value).
// prediction: [B=32, 255, 52, 52] f32 ; anchors: [3,2] f32
// out: [B, 52*52*3, 85] f32 ; flat out elem = (b*2704 + s)*255 + c.
//
// Group = 16 consecutive s: input = one aligned 64B line per c-row (255
// exclusive lines); output = 4080 contiguous floats = 255 aligned lines.
// Decode folded into load phase (c = idx>>2 per-thread constant; specials
// {0-3,85-88,170-173} touch 3/16 wave-iters); store phase = pure copy.
// Pipeline: g1's global loads issue before g0's store phase -> HBM read
// latency hides under the write stream. Grid 2704 = 8 XCD x 338 slots.

#define GG 52
#define NROWS 255
#define PLANE 2704             // 52*52, flat s
#define L2E 1.442695040889f

typedef float f32x4 __attribute__((ext_vector_type(4)));

__device__ __forceinline__ float fast_sigmoid(float x) {
    return __builtin_amdgcn_rcpf(1.0f + __builtin_amdgcn_exp2f(-L2E * x));
}

// decode one staged f32x4 (by value -> stays in registers)
__device__ __forceinline__ f32x4 decode4(f32x4 u, int idx, int gj0, int rem0,
                                         float a0x, float a0y, float a1x,
                                         float a1y, float a2x, float a2y) {
    const int c = idx >> 2;
    const int q = idx & 3;

    f32x4 r;
    r.x = fast_sigmoid(u.x);
    r.y = fast_sigmoid(u.y);
    r.z = fast_sigmoid(u.z);
    r.w = fast_sigmoid(u.w);

    const bool sp0 = c < 4;
    const bool sp1 = (unsigned)(c - 85)  < 4u;
    const bool sp2 = (unsigned)(c - 170) < 4u;
    if (__builtin_expect(sp0 | sp1 | sp2, 0)) {
        const int attr = sp0 ? c : (sp1 ? c - 85 : c - 170);
        const float ancx = sp0 ? a0x : (sp1 ? a1x : a2x);
        const float ancy = sp0 ? a0y : (sp1 ? a1y : a2y);
        const float anc  = (attr == 2) ? ancx : ancy;
        #pragma unroll
        for (int k = 0; k < 4; ++k) {
            const int rem = rem0 + 4 * q + k;   // < 68: one wrap max
            const int wv  = (rem >= GG) ? 1 : 0;
            const int gi  = rem - (wv ? GG : 0);
            const int gj  = gj0 + wv;
            const float x  = u[k];
            const float sg = r[k];
            float rr;
            if (attr == 0)      rr = (sg + (float)gi) * 8.0f;
            else if (attr == 1) rr = (sg + (float)gj) * 8.0f;
            else                rr = __builtin_amdgcn_exp2f(L2E * x) * anc;
            r[k] = rr;
        }
    }
    return r;
}

__device__ __forceinline__ void scatter4(float* __restrict__ tile, int idx,
                                         f32x4 r) {
    // element (c = idx>>2, s_l = 4*(idx&3)+k) -> e = s_l*255 + c
    const int e = (idx & 3) * 4 * NROWS + (idx >> 2);
    tile[e            ] = r.x;
    tile[e +     NROWS] = r.y;
    tile[e + 2 * NROWS] = r.z;
    tile[e + 3 * NROWS] = r.w;
}

__global__ __launch_bounds__(256, 8)
void detect_decode_kernel(const float* __restrict__ in,
                          const float* __restrict__ anchors,
                          float* __restrict__ out) {
    __shared__ float tile[16 * NROWS];   // 16,320 B, FINAL values, output order

    const int B    = blockIdx.x;         // 2704 = 8 * 338
    const int xcd  = B & 7;
    const int slot = B >> 3;             // 0..337
    const int g0   = xcd * 676 + slot;   // this block: groups g0, g0+338
    const int g1   = g0 + 338;
    const int t    = threadIdx.x;

    const int i0 = t;
    const int i1 = t + 256;
    const int i2 = t + 512;
    const int i3 = (t + 768 < 1020) ? t + 768 : 1019;   // clamp (c=254: plain)

    const float a0x = anchors[0], a0y = anchors[1];
    const float a1x = anchors[2], a1y = anchors[3];
    const float a2x = anchors[4], a2y = anchors[5];

    // group geometry (block-uniform scalar math)
    const int b0_  = g0 / 169;
    const int s00  = (g0 - b0_ * 169) * 16;
    const int gj00 = s00 / GG;
    const int rem00 = s00 - gj00 * GG;
    const float* __restrict__ src0 = in + (size_t)b0_ * NROWS * PLANE + s00;
    float* __restrict__ dst0 = out + ((size_t)b0_ * PLANE + s00) * NROWS;

    const int b1_  = g1 / 169;
    const int s01  = (g1 - b1_ * 169) * 16;
    const int gj01 = s01 / GG;
    const int rem01 = s01 - gj01 * GG;
    const float* __restrict__ src1 = in + (size_t)b1_ * NROWS * PLANE + s01;
    float* __restrict__ dst1 = out + ((size_t)b1_ * PLANE + s01) * NROWS;

    // ---- g0: load (4-deep MLP, named regs) ----
    const f32x4 va = *reinterpret_cast<const f32x4*>(src0 + (size_t)(i0 >> 2) * PLANE + (i0 & 3) * 4);
    const f32x4 vb = *reinterpret_cast<const f32x4*>(src0 + (size_t)(i1 >> 2) * PLANE + (i1 & 3) * 4);
    const f32x4 vc = *reinterpret_cast<const f32x4*>(src0 + (size_t)(i2 >> 2) * PLANE + (i2 & 3) * 4);
    const f32x4 vd = *reinterpret_cast<const f32x4*>(src0 + (size_t)(i3 >> 2) * PLANE + (i3 & 3) * 4);

    // ---- g0: decode + scatter (v regs die here) ----
    scatter4(tile, i0, decode4(va, i0, gj00, rem00, a0x, a0y, a1x, a1y, a2x, a2y));
    scatter4(tile, i1, decode4(vb, i1, gj00, rem00, a0x, a0y, a1x, a1y, a2x, a2y));
    scatter4(tile, i2, decode4(vc, i2, gj00, rem00, a0x, a0y, a1x, a1y, a2x, a2y));
    scatter4(tile, i3, decode4(vd, i3, gj00, rem00, a0x, a0y, a1x, a1y, a2x, a2y));

    __syncthreads();

    // ---- g1: issue loads EARLY (latency hides under g0's store phase) ----
    const f32x4 wa = *reinterpret_cast<const f32x4*>(src1 + (size_t)(i0 >> 2) * PLANE + (i0 & 3) * 4);
    const f32x4 wb = *reinterpret_cast<const f32x4*>(src1 + (size_t)(i1 >> 2) * PLANE + (i1 & 3) * 4);
    const f32x4 wc = *reinterpret_cast<const f32x4*>(src1 + (size_t)(i2 >> 2) * PLANE + (i2 & 3) * 4);
    const f32x4 wd = *reinterpret_cast<const f32x4*>(src1 + (size_t)(i3 >> 2) * PLANE + (i3 & 3) * 4);

    // ---- g0: read tile + store (pure copy) ----
    {
        const f32x4 u0 = *reinterpret_cast<const f32x4*>(&tile[4 * i0]);
        const f32x4 u1 = *reinterpret_cast<const f32x4*>(&tile[4 * i1]);
        const f32x4 u2 = *reinterpret_cast<const f32x4*>(&tile[4 * i2]);
        const f32x4 u3 = *reinterpret_cast<const f32x4*>(&tile[4 * i3]);
        *reinterpret_cast<f32x4*>(dst0 + 4 * i0) = u0;
        *reinterpret_cast<f32x4*>(dst0 + 4 * i1) = u1;
        *reinterpret_cast<f32x4*>(dst0 + 4 * i2) = u2;
        *reinterpret_cast<f32x4*>(dst0 + 4 * i3) = u3;
    }

    __syncthreads();                 // all waves done reading tile

    // ---- g1: decode (waits vmcnt here) + scatter ----
    scatter4(tile, i0, decode4(wa, i0, gj01, rem01, a0x, a0y, a1x, a1y, a2x, a2y));
    scatter4(tile, i1, decode4(wb, i1, gj01, rem01, a0x, a0y, a1x, a1y, a2x, a2y));
    scatter4(tile, i2, decode4(wc, i2, gj01, rem01, a0x, a0y, a1x, a1y, a2x, a2y));
    scatter4(tile, i3, decode4(wd, i3, gj01, rem01, a0x, a0y, a1x, a1y, a2x, a2y));

    __syncthreads();

    // ---- g1: read tile + store ----
    {
        const f32x4 u0 = *reinterpret_cast<const f32x4*>(&tile[4 * i0]);
        const f32x4 u1 = *reinterpret_cast<const f32x4*>(&tile[4 * i1]);
        const f32x4 u2 = *reinterpret_cast<const f32x4*>(&tile[4 * i2]);
        const f32x4 u3 = *reinterpret_cast<const f32x4*>(&tile[4 * i3]);
        *reinterpret_cast<f32x4*>(dst1 + 4 * i0) = u0;
        *reinterpret_cast<f32x4*>(dst1 + 4 * i1) = u1;
        *reinterpret_cast<f32x4*>(dst1 + 4 * i2) = u2;
        *reinterpret_cast<f32x4*>(dst1 + 4 * i3) = u3;
    }
}

extern "C" void kernel_launch(void* const* d_in, const int* in_sizes, int n_in,
                              void* d_out, int out_size, void* d_ws, size_t ws_size,
                              hipStream_t stream) {
    const float* pred    = (const float*)d_in[0];
    const float* anchors = (const float*)d_in[1];
    float* out = (float*)d_out;

    detect_decode_kernel<<<2704, 256, 0, stream>>>(pred, anchors, out);
}

// Round 18
// 31.025 us; speedup vs baseline: 1.5962x; 1.0249x over previous
//
#include <hip/hip_runtime.h>
#include <math.h>

// YOLOv3 detection-head decode — 32-s groups: 128B read bursts per c-row.
// prediction: [B=32, 255, 52, 52] f32 ; anchors: [3,2] f32
// out: [B, 52*52*3, 85] f32 ; flat out elem = (b*2704 + s)*255 + c.
//
// R18 change vs R15: group = 32 consecutive s (was 16) -> the strided read
// stream becomes TWO consecutive 64B lines (128B) per c-row instead of one
// isolated line, halving DRAM page-activate rate on the read side (the one
// untested suspect; all else measured non-binding). 512-thread blocks,
// LDS 32,640B -> 4 blocks/CU = 2048 thr = 100% occupancy.
// Per b: 84 groups of 32 s + 1 tail group of 16 s. Grid 2720 = 8 XCD x 340.
// Decode folded into load phase (c per-thread constant; specials in few
// wave-iters); store phase = pure contiguous copy; one barrier.

#define GG 52
#define NROWS 255
#define PLANE 2704             // 52*52, flat s
#define L2E 1.442695040889f

typedef float f32x4 __attribute__((ext_vector_type(4)));

__device__ __forceinline__ float fast_sigmoid(float x) {
    return __builtin_amdgcn_rcpf(1.0f + __builtin_amdgcn_exp2f(-L2E * x));
}

template<int NS>   // s-values per group: 32 (bulk) or 16 (tail)
__device__ __forceinline__ void body(const float* __restrict__ src,
                                     float* __restrict__ dst,
                                     int gj0, int rem0, int t,
                                     float* __restrict__ tile,
                                     float a0x, float a0y, float a1x,
                                     float a1y, float a2x, float a2y) {
    constexpr int QPR  = NS / 4;             // float4 per c-row: 8 or 4
    constexpr int TOTQ = NROWS * QPR;        // 2040 or 1020
    constexpr int NIT  = (TOTQ + 511) / 512; // 4 or 2

    // ---- load + decode + scatter ----
    #pragma unroll
    for (int it = 0; it < NIT; ++it) {
        int idx = t + it * 512;
        if (idx > TOTQ - 1) idx = TOTQ - 1;   // clamp (c=254: plain sigmoid)
        const int c = idx / QPR;              // QPR pow2 -> shift
        const int q = idx - c * QPR;

        const f32x4 u = *reinterpret_cast<const f32x4*>(
            src + (size_t)c * PLANE + 4 * q);

        f32x4 r;
        r.x = fast_sigmoid(u.x);
        r.y = fast_sigmoid(u.y);
        r.z = fast_sigmoid(u.z);
        r.w = fast_sigmoid(u.w);

        const bool sp0 = c < 4;
        const bool sp1 = (unsigned)(c - 85)  < 4u;
        const bool sp2 = (unsigned)(c - 170) < 4u;
        if (__builtin_expect(sp0 | sp1 | sp2, 0)) {
            const int attr = sp0 ? c : (sp1 ? c - 85 : c - 170);
            const float ancx = sp0 ? a0x : (sp1 ? a1x : a2x);
            const float ancy = sp0 ? a0y : (sp1 ? a1y : a2y);
            const float anc  = (attr == 2) ? ancx : ancy;
            #pragma unroll
            for (int k = 0; k < 4; ++k) {
                const int rem = rem0 + 4 * q + k;   // <= 51+31: one wrap max
                const int wv  = (rem >= GG) ? 1 : 0;
                const int gi  = rem - (wv ? GG : 0);
                const int gj  = gj0 + wv;
                const float x  = u[k];
                const float sg = r[k];
                float rr;
                if (attr == 0)      rr = (sg + (float)gi) * 8.0f;
                else if (attr == 1) rr = (sg + (float)gj) * 8.0f;
                else                rr = __builtin_amdgcn_exp2f(L2E * x) * anc;
                r[k] = rr;
            }
        }

        // element (c, s_l = 4q+k) -> e = s_l*255 + c
        const int e = 4 * q * NROWS + c;
        tile[e            ] = r.x;
        tile[e +     NROWS] = r.y;
        tile[e + 2 * NROWS] = r.z;
        tile[e + 3 * NROWS] = r.w;
    }

    __syncthreads();

    // ---- store: pure contiguous copy ----
    #pragma unroll
    for (int it = 0; it < NIT; ++it) {
        int i = t + it * 512;
        if (i > TOTQ - 1) i = TOTQ - 1;
        const f32x4 u = *reinterpret_cast<const f32x4*>(&tile[4 * i]);
        *reinterpret_cast<f32x4*>(dst + 4 * i) = u;
    }
}

__global__ __launch_bounds__(512, 8)
void detect_decode_kernel(const float* __restrict__ in,
                          const float* __restrict__ anchors,
                          float* __restrict__ out) {
    __shared__ float tile[32 * NROWS];   // 32,640 B -> 4 blocks/CU

    // XCD swizzle: XCD x owns contiguous group range
    const int B   = blockIdx.x;          // 2720 = 8 * 340
    const int g   = (B & 7) * 340 + (B >> 3);
    const int b   = g / 85;              // magic div
    const int loc = g - b * 85;          // 0..84
    const int s0  = loc * 32;            // loc==84 -> 2688 (tail, 16 s)
    const int t   = threadIdx.x;

    const int gj0  = s0 / GG;            // block-uniform
    const int rem0 = s0 - gj0 * GG;

    const float* __restrict__ src = in + (size_t)b * NROWS * PLANE + s0;
    float* __restrict__ dst = out + ((size_t)b * PLANE + s0) * NROWS;

    const float a0x = anchors[0], a0y = anchors[1];
    const float a1x = anchors[2], a1y = anchors[3];
    const float a2x = anchors[4], a2y = anchors[5];

    if (loc < 84)
        body<32>(src, dst, gj0, rem0, t, tile, a0x, a0y, a1x, a1y, a2x, a2y);
    else
        body<16>(src, dst, gj0, rem0, t, tile, a0x, a0y, a1x, a1y, a2x, a2y);
}

extern "C" void kernel_launch(void* const* d_in, const int* in_sizes, int n_in,
                              void* d_out, int out_size, void* d_ws, size_t ws_size,
                              hipStream_t stream) {
    const float* pred    = (const float*)d_in[0];
    const float* anchors = (const float*)d_in[1];
    float* out = (float*)d_out;

    detect_decode_kernel<<<2720, 512, 0, stream>>>(pred, anchors, out);
}